// Round 1
// baseline (3846.336 us; speedup 1.0000x reference)
//
#include <hip/hip_runtime.h>
#include <stdint.h>

#define BB 2
#define CC 256
#define NN 65536
#define LL 8

// meta[] layout (ints)
#define M_CNTC 0
#define M_CNTS 8
#define M_OFFC 16
#define M_OFFS 24
#define M_CURC 32
#define M_CURS 40
#define M_GUIDE 48

// ---------------- histogram ----------------
__global__ void k_hist(const int* __restrict__ cm, const int* __restrict__ sm,
                       int* __restrict__ meta)
{
    __shared__ int lc[LL], ls[LL];
    int t = threadIdx.x;
    if (t < LL) { lc[t] = 0; ls[t] = 0; }
    __syncthreads();
    int n = blockIdx.x * 256 + t;           // grid 256 x 256 == NN exactly
    atomicAdd(&lc[cm[n] & 7], 1);
    atomicAdd(&ls[sm[n] & 7], 1);
    __syncthreads();
    if (t < LL) {
        atomicAdd(&meta[M_CNTC + t], lc[t]);
        atomicAdd(&meta[M_CNTS + t], ls[t]);
    }
}

// ---------------- scan: offsets, cursors, guide flags ----------------
__global__ void k_scan(int* __restrict__ meta)
{
    if (threadIdx.x == 0 && blockIdx.x == 0) {
        int oc = 0, os = 0;
        for (int l = 0; l < LL; l++) {
            meta[M_OFFC + l] = oc; meta[M_CURC + l] = oc;
            meta[M_OFFS + l] = os; meta[M_CURS + l] = os;
            oc += meta[M_CNTC + l];
            os += meta[M_CNTS + l];
        }
        for (int l = 0; l < LL; l++) {
            int a = meta[M_CNTC + l], b = meta[M_CNTS + l];
            meta[M_GUIDE + l] = (a > 10 && b > 10 && a < 10 * b && b < 10 * a) ? 1 : 0;
        }
    }
}

// ---------------- dest ranks (wave-aggregated atomics) ----------------
__global__ void k_dest(const int* __restrict__ cm, const int* __restrict__ sm,
                       int* __restrict__ meta, int* __restrict__ pdc, int* __restrict__ pds)
{
    int n = blockIdx.x * 256 + threadIdx.x;     // grid 256x256 == NN exactly
    int lane = threadIdx.x & 63;
    unsigned long long below = (1ull << lane) - 1ull;
    int lc = cm[n] & 7, ls = sm[n] & 7;
    int dc = 0, dsv = 0;
    for (int lab = 0; lab < LL; lab++) {
        unsigned long long m = __ballot(lc == lab);
        if (m) {
            int leader = __ffsll((unsigned long long)m) - 1;
            int cntw = __popcll(m);
            int base = 0;
            if (lane == leader) base = atomicAdd(&meta[M_CURC + lab], cntw);
            base = __shfl(base, leader, 64);
            if (lc == lab) dc = base + __popcll(m & below);
        }
        unsigned long long m2 = __ballot(ls == lab);
        if (m2) {
            int leader = __ffsll((unsigned long long)m2) - 1;
            int cntw = __popcll(m2);
            int base = 0;
            if (lane == leader) base = atomicAdd(&meta[M_CURS + lab], cntw);
            base = __shfl(base, leader, 64);
            if (ls == lab) dsv = base + __popcll(m2 & below);
        }
    }
    pdc[n] = dc | (lc << 16);
    pds[n] = dsv | (ls << 16);
}

// ---------------- gather to compacted X + per-label channel sums ----------------
__global__ void k_gather(const float* __restrict__ feat, const int* __restrict__ pd,
                         float* __restrict__ X, float* __restrict__ sums)
{
    // grid: x = 8 chunks of 8192 px, y = channel c, z = batch b
    __shared__ float sacc[LL][256];
    int t = threadIdx.x;
    int c = blockIdx.y, b = blockIdx.z;
    int n0 = blockIdx.x * 8192;
    for (int r = 0; r < LL; r++) sacc[r][t] = 0.f;
    const float* row = feat + ((size_t)b * CC + c) * NN;
    float* Xrow = X + ((size_t)b * CC + c) * NN;
    for (int it = 0; it < 8; it++) {
        int n = n0 + it * 1024 + t * 4;
        float4 v = *(const float4*)(row + n);
        int4 pp = *(const int4*)(pd + n);
        int d0 = pp.x & 0xFFFF, l0 = pp.x >> 16;
        int d1 = pp.y & 0xFFFF, l1 = pp.y >> 16;
        int d2 = pp.z & 0xFFFF, l2 = pp.z >> 16;
        int d3 = pp.w & 0xFFFF, l3 = pp.w >> 16;
        Xrow[d0] = v.x; sacc[l0][t] += v.x;
        Xrow[d1] = v.y; sacc[l1][t] += v.y;
        Xrow[d2] = v.z; sacc[l2][t] += v.z;
        Xrow[d3] = v.w; sacc[l3][t] += v.w;
    }
    __syncthreads();
    int r = t >> 5, q = t & 31;
    float s = 0.f;
    for (int k = q; k < 256; k += 32) s += sacc[r][k];
    for (int off = 16; off; off >>= 1) s += __shfl_down(s, off, 32);
    if (q == 0) atomicAdd(&sums[((size_t)b * LL + r) * CC + c], s);
}

// ---------------- syrk: M2 += X_tileR * X_tileC^T over label pixels ----------------
__global__ __launch_bounds__(256) void k_syrk(const float* __restrict__ X, float* __restrict__ M2,
                                              const int* __restrict__ meta, int offBase, int cntBase)
{
    int z = blockIdx.z; int b = z >> 3, l = z & 7;
    if (!meta[M_GUIDE + l]) return;
    int cnt = meta[cntBase + l];
    int off = meta[offBase + l];
    int KCH = gridDim.x;
    int clen = (cnt + KCH - 1) / KCH;
    int lend = off + cnt;
    int p0 = off + blockIdx.x * clen;
    if (p0 >= lend) return;
    int pend = min(p0 + clen, lend);
    int tileR = (blockIdx.y >> 1) * 128;
    int tileCo = (blockIdx.y & 1) * 128;

    __shared__ float Ast[32][132];
    __shared__ float Bst[32][132];

    const float* Xb = X + (size_t)b * CC * NN;
    int t = threadIdx.x;
    int ty = t >> 4, tx = t & 15;

    float acc[8][8];
#pragma unroll
    for (int i = 0; i < 8; i++)
#pragma unroll
        for (int j = 0; j < 8; j++) acc[i][j] = 0.f;

    for (int k0 = p0; k0 < pend; k0 += 32) {
#pragma unroll
        for (int q = 0; q < 16; q++) {
            int slot = q * 256 + t;
            int r = slot >> 5, kk = slot & 31;
            int p = k0 + kk;
            float av = 0.f, bv = 0.f;
            if (p < pend) {
                av = Xb[(size_t)(tileR + r) * NN + p];
                bv = Xb[(size_t)(tileCo + r) * NN + p];
            }
            Ast[kk][r] = av;
            Bst[kk][r] = bv;
        }
        __syncthreads();
#pragma unroll 4
        for (int kk = 0; kk < 32; kk++) {
            float4 a0 = *(const float4*)&Ast[kk][ty * 8];
            float4 a1 = *(const float4*)&Ast[kk][ty * 8 + 4];
            float4 b0 = *(const float4*)&Bst[kk][tx * 8];
            float4 b1 = *(const float4*)&Bst[kk][tx * 8 + 4];
            float a[8]  = {a0.x, a0.y, a0.z, a0.w, a1.x, a1.y, a1.z, a1.w};
            float bb[8] = {b0.x, b0.y, b0.z, b0.w, b1.x, b1.y, b1.z, b1.w};
#pragma unroll
            for (int i = 0; i < 8; i++)
#pragma unroll
                for (int j = 0; j < 8; j++)
                    acc[i][j] += a[i] * bb[j];
        }
        __syncthreads();
    }

    float* Mb = M2 + (size_t)z * CC * CC;
#pragma unroll
    for (int i = 0; i < 8; i++) {
        int row = tileR + ty * 8 + i;
#pragma unroll
        for (int j = 0; j < 8; j++) {
            int col = tileCo + tx * 8 + j;
            atomicAdd(&Mb[(size_t)row * CC + col], acc[i][j]);
        }
    }
}

// ---------------- finalize: cov = (M2 - a*mu*mu^T)/(a-1), in place ----------------
__global__ void k_finalize(float* __restrict__ M2c, float* __restrict__ M2s,
                           const float* __restrict__ sums_c, const float* __restrict__ sums_s,
                           const int* __restrict__ meta)
{
    int y = blockIdx.y; int l = y & 7, b = (y >> 3) & 1, st = y >> 4;
    if (!meta[M_GUIDE + l]) return;
    float a = (float)meta[(st ? M_CNTS : M_CNTC) + l];
    float* M = (st ? M2s : M2c) + ((size_t)(b * LL + l)) * CC * CC;
    const float* su = (st ? sums_s : sums_c) + ((size_t)(b * LL + l)) * CC;
    int idx = blockIdx.x * 256 + threadIdx.x;
    int row = idx >> 8, col = idx & 255;
    float mu_r = su[row] / a, mu_c = su[col] / a;
    M[idx] = (M[idx] - a * mu_r * mu_c) / (a - 1.f);
}

// ---------------- Cholesky (in place, lower); content also writes L^T ----------------
__global__ __launch_bounds__(256) void k_chol(float* __restrict__ M2c, float* __restrict__ M2s,
                                              float* __restrict__ LcT, const int* __restrict__ meta)
{
    int z = blockIdx.x; int l = z & 7, b = (z >> 3) & 1, st = z >> 4;
    if (!meta[M_GUIDE + l]) return;
    float* A = (st ? M2s : M2c) + ((size_t)(b * LL + l)) * CC * CC;
    float* Lt = st ? (float*)0 : (LcT + ((size_t)(b * LL + l)) * CC * CC);
    __shared__ float rowj[256];
    __shared__ float red[4];
    __shared__ float sh_ljj;
    int t = threadIdx.x;
    for (int j = 0; j < CC; j++) {
        for (int k = t; k < j; k += 256) rowj[k] = A[(size_t)j * CC + k];
        __syncthreads();
        float s = 0.f;
        for (int k = t; k < j; k += 256) s += rowj[k] * rowj[k];
        for (int o = 32; o; o >>= 1) s += __shfl_down(s, o, 64);
        if ((t & 63) == 0) red[t >> 6] = s;
        __syncthreads();
        if (t == 0) {
            float d = A[(size_t)j * CC + j] - (red[0] + red[1] + red[2] + red[3]);
            float ljj = sqrtf(fmaxf(d, 1e-20f));
            sh_ljj = ljj;
            A[(size_t)j * CC + j] = ljj;
            if (Lt) Lt[(size_t)j * CC + j] = ljj;
        }
        __syncthreads();
        float ljj = sh_ljj;
        int i = t;
        if (i > j) {
            const float* Ai = A + (size_t)i * CC;
            float s2 = 0.f;
            int k = 0;
            for (; k + 3 < j; k += 4) {
                float4 av = *(const float4*)&Ai[k];
                float4 rv = *(const float4*)&rowj[k];
                s2 += av.x * rv.x + av.y * rv.y + av.z * rv.z + av.w * rv.w;
            }
            for (; k < j; k++) s2 += Ai[k] * rowj[k];
            float lij = (Ai[j] - s2) / ljj;
            A[(size_t)i * CC + j] = lij;
            if (Lt) Lt[(size_t)j * CC + i] = lij;
        }
        __syncthreads();
    }
}

// ---------------- solve T*Lc = Ls (writes T^T), then v = mu_s - T mu_c ----------------
__global__ __launch_bounds__(256) void k_solve(const float* __restrict__ LcT, const float* __restrict__ M2s,
                                               float* __restrict__ TT, float* __restrict__ vv,
                                               const float* __restrict__ sums_c, const float* __restrict__ sums_s,
                                               const int* __restrict__ meta)
{
    int y = blockIdx.y; int l = y & 7;
    if (!meta[M_GUIDE + l]) return;
    const float* Lc_t = LcT + (size_t)y * CC * CC;
    const float* Ls = M2s + (size_t)y * CC * CC;
    float* Tt = TT + (size_t)y * CC * CC;
    __shared__ float m[32][257];
    __shared__ float lrow[256];
    int t = threadIdx.x;
    int g = t >> 3, tt = t & 7;
    int c = blockIdx.x * 32 + g;
    for (int i = CC - 1; i >= 0; i--) {
        lrow[t] = Lc_t[(size_t)i * CC + t];
        __syncthreads();
        if (c >= i) {
            float s = 0.f;
            for (int k = i + 1 + tt; k <= c; k += 8) s += lrow[k] * m[g][k];
            s += __shfl_down(s, 4, 8);
            s += __shfl_down(s, 2, 8);
            s += __shfl_down(s, 1, 8);
            if (tt == 0) {
                float val = (Ls[(size_t)c * CC + i] - s) / lrow[i];
                m[g][i] = val;
                Tt[(size_t)i * CC + c] = val;
            }
        }
        __syncthreads();
    }
    float aF = (float)meta[M_CNTC + l], bF = (float)meta[M_CNTS + l];
    const float* sc = sums_c + (size_t)y * CC;
    const float* ss = sums_s + (size_t)y * CC;
    float s = 0.f;
    for (int e = tt; e <= c; e += 8) s += m[g][e] * sc[e];
    s += __shfl_down(s, 4, 8);
    s += __shfl_down(s, 2, 8);
    s += __shfl_down(s, 1, 8);
    if (tt == 0) vv[(size_t)y * CC + c] = ss[c] / bF - s / aF;
}

// ---------------- coloring GEMM: O = T*Xc + v (compacted pixel space) ----------------
__global__ __launch_bounds__(256) void k_color(const float* __restrict__ X, const float* __restrict__ TT,
                                               const float* __restrict__ vv, float* __restrict__ O,
                                               const int* __restrict__ meta)
{
    int z = blockIdx.z; int b = z >> 3, l = z & 7;
    if (!meta[M_GUIDE + l]) return;
    int cnt = meta[M_CNTC + l], off = meta[M_OFFC + l];
    int lend = off + cnt;
    int p0 = off + blockIdx.x * 128;
    if (p0 >= lend) return;
    int pend = min(p0 + 128, lend);
    int c0 = blockIdx.y * 128;

    __shared__ float Ast[32][132];
    __shared__ float Bst[32][132];

    const float* Xb = X + (size_t)b * CC * NN;
    const float* Tb = TT + ((size_t)(b * LL + l)) * CC * CC;   // [e][c]
    const float* vb = vv + ((size_t)(b * LL + l)) * CC;
    int t = threadIdx.x;
    int ty = t >> 4, tx = t & 15;

    float4 v0 = *(const float4*)&vb[c0 + ty * 8];
    float4 v1 = *(const float4*)&vb[c0 + ty * 8 + 4];
    float vi[8] = {v0.x, v0.y, v0.z, v0.w, v1.x, v1.y, v1.z, v1.w};
    float acc[8][8];
#pragma unroll
    for (int i = 0; i < 8; i++)
#pragma unroll
        for (int j = 0; j < 8; j++) acc[i][j] = vi[i];

    for (int e0 = 0; e0 < CC; e0 += 32) {
#pragma unroll
        for (int q = 0; q < 4; q++) {
            int slot = q * 256 + t;
            int kk = slot >> 5, cq = slot & 31;
            *(float4*)&Ast[kk][cq * 4] = *(const float4*)&Tb[(size_t)(e0 + kk) * CC + c0 + cq * 4];
        }
#pragma unroll
        for (int q = 0; q < 16; q++) {
            int slot = q * 256 + t;
            int kk = slot >> 7, px = slot & 127;
            int p = p0 + px;
            Bst[kk][px] = (p < pend) ? Xb[(size_t)(e0 + kk) * NN + p] : 0.f;
        }
        __syncthreads();
#pragma unroll 4
        for (int kk = 0; kk < 32; kk++) {
            float4 a0 = *(const float4*)&Ast[kk][ty * 8];
            float4 a1 = *(const float4*)&Ast[kk][ty * 8 + 4];
            float4 b0 = *(const float4*)&Bst[kk][tx * 8];
            float4 b1 = *(const float4*)&Bst[kk][tx * 8 + 4];
            float a[8]  = {a0.x, a0.y, a0.z, a0.w, a1.x, a1.y, a1.z, a1.w};
            float bb[8] = {b0.x, b0.y, b0.z, b0.w, b1.x, b1.y, b1.z, b1.w};
#pragma unroll
            for (int i = 0; i < 8; i++)
#pragma unroll
                for (int j = 0; j < 8; j++)
                    acc[i][j] += a[i] * bb[j];
        }
        __syncthreads();
    }

    float* Ob = O + (size_t)b * CC * NN;
#pragma unroll
    for (int i = 0; i < 8; i++) {
        int row = c0 + ty * 8 + i;
        float* orow = Ob + (size_t)row * NN;
#pragma unroll
        for (int j = 0; j < 8; j++) {
            int p = p0 + tx * 8 + j;
            if (p < pend) orow[p] = acc[i][j];
        }
    }
}

// ---------------- final scatter back to natural pixel order ----------------
__global__ void k_scatter(const float* __restrict__ cf, const float* __restrict__ O,
                          const int* __restrict__ pd, float* __restrict__ out,
                          const int* __restrict__ meta)
{
    __shared__ int gd[LL];
    int t = threadIdx.x;
    if (t < LL) gd[t] = meta[M_GUIDE + t];
    __syncthreads();
    int c = blockIdx.y, b = blockIdx.z;
    int n = blockIdx.x * 1024 + t * 4;
    const float* cfr = cf + ((size_t)b * CC + c) * NN;
    const float* Or = O + ((size_t)b * CC + c) * NN;
    float4 v = *(const float4*)(cfr + n);
    int4 pp = *(const int4*)(pd + n);
    float r0 = (gd[pp.x >> 16]) ? Or[pp.x & 0xFFFF] : v.x;
    float r1 = (gd[pp.y >> 16]) ? Or[pp.y & 0xFFFF] : v.y;
    float r2 = (gd[pp.z >> 16]) ? Or[pp.z & 0xFFFF] : v.z;
    float r3 = (gd[pp.w >> 16]) ? Or[pp.w & 0xFFFF] : v.w;
    float4 r = {r0, r1, r2, r3};
    *(float4*)(out + ((size_t)b * CC + c) * NN + n) = r;
}

extern "C" void kernel_launch(void* const* d_in, const int* in_sizes, int n_in,
                              void* d_out, int out_size, void* d_ws, size_t ws_size,
                              hipStream_t stream)
{
    const float* c_feat = (const float*)d_in[0];
    const float* s_feat = (const float*)d_in[1];
    const int* cm = (const int*)d_in[2];
    const int* sm = (const int*)d_in[3];
    float* out = (float*)d_out;

    float* X2 = (float*)d_ws;                              // B*C*N floats: Xs, then compacted colored output
    float* M2c = X2 + (size_t)BB * CC * NN;                // B*L*C*C
    float* M2s = M2c + (size_t)BB * LL * CC * CC;
    float* LcT = M2s + (size_t)BB * LL * CC * CC;
    float* T_T = LcT + (size_t)BB * LL * CC * CC;
    float* sums_c = T_T + (size_t)BB * LL * CC * CC;
    float* sums_s = sums_c + BB * LL * CC;
    float* vv = sums_s + BB * LL * CC;
    int* pdc = (int*)(vv + BB * LL * CC);
    int* pds = pdc + NN;
    int* meta = pds + NN;
    size_t need = (size_t)((char*)(meta + 64) - (char*)d_ws);
    if (ws_size < need) return;

    float* Xc = out;   // d_out doubles as compacted-content scratch until the final scatter

    hipMemsetAsync(meta, 0, 64 * sizeof(int), stream);
    hipMemsetAsync(sums_c, 0, (size_t)2 * BB * LL * CC * sizeof(float), stream);
    hipMemsetAsync(M2c, 0, (size_t)2 * BB * LL * CC * CC * sizeof(float), stream);
    hipMemsetAsync(T_T, 0, (size_t)BB * LL * CC * CC * sizeof(float), stream);

    k_hist<<<256, 256, 0, stream>>>(cm, sm, meta);
    k_scan<<<1, 64, 0, stream>>>(meta);
    k_dest<<<256, 256, 0, stream>>>(cm, sm, meta, pdc, pds);
    k_gather<<<dim3(8, CC, BB), 256, 0, stream>>>(c_feat, pdc, Xc, sums_c);
    k_gather<<<dim3(8, CC, BB), 256, 0, stream>>>(s_feat, pds, X2, sums_s);
    k_syrk<<<dim3(16, 4, 16), 256, 0, stream>>>(Xc, M2c, meta, M_OFFC, M_CNTC);
    k_syrk<<<dim3(16, 4, 16), 256, 0, stream>>>(X2, M2s, meta, M_OFFS, M_CNTS);
    k_finalize<<<dim3(256, 32), 256, 0, stream>>>(M2c, M2s, sums_c, sums_s, meta);
    k_chol<<<32, 256, 0, stream>>>(M2c, M2s, LcT, meta);
    k_solve<<<dim3(8, 16), 256, 0, stream>>>(LcT, M2s, T_T, vv, sums_c, sums_s, meta);
    k_color<<<dim3(512, 2, 16), 256, 0, stream>>>(Xc, T_T, vv, X2, meta);
    k_scatter<<<dim3(64, CC, BB), 256, 0, stream>>>(c_feat, X2, pdc, out, meta);
}

// Round 2
// 2320.402 us; speedup vs baseline: 1.6576x; 1.6576x over previous
//
#include <hip/hip_runtime.h>
#include <stdint.h>

#define BB 2
#define CC 256
#define NN 65536
#define LL 8

// meta[] layout (ints)
#define M_CNTC 0
#define M_CNTS 8
#define M_OFFC 16
#define M_OFFS 24
#define M_CURC 32
#define M_CURS 40
#define M_GUIDE 48

typedef const __attribute__((address_space(1))) unsigned int* gp1_t;
typedef __attribute__((address_space(3))) unsigned int* lp3_t;

__device__ __forceinline__ void gload16(const float* g, float* l) {
    __builtin_amdgcn_global_load_lds((gp1_t)(const void*)g, (lp3_t)(void*)l, 16, 0, 0);
}

// ---------------- histogram ----------------
__global__ void k_hist(const int* __restrict__ cm, const int* __restrict__ sm,
                       int* __restrict__ meta)
{
    __shared__ int lc[LL], ls[LL];
    int t = threadIdx.x;
    if (t < LL) { lc[t] = 0; ls[t] = 0; }
    __syncthreads();
    int n = blockIdx.x * 256 + t;
    atomicAdd(&lc[cm[n] & 7], 1);
    atomicAdd(&ls[sm[n] & 7], 1);
    __syncthreads();
    if (t < LL) {
        atomicAdd(&meta[M_CNTC + t], lc[t]);
        atomicAdd(&meta[M_CNTS + t], ls[t]);
    }
}

// ---------------- scan ----------------
__global__ void k_scan(int* __restrict__ meta)
{
    if (threadIdx.x == 0 && blockIdx.x == 0) {
        int oc = 0, os = 0;
        for (int l = 0; l < LL; l++) {
            meta[M_OFFC + l] = oc; meta[M_CURC + l] = oc;
            meta[M_OFFS + l] = os; meta[M_CURS + l] = os;
            oc += meta[M_CNTC + l];
            os += meta[M_CNTS + l];
        }
        for (int l = 0; l < LL; l++) {
            int a = meta[M_CNTC + l], b = meta[M_CNTS + l];
            meta[M_GUIDE + l] = (a > 10 && b > 10 && a < 10 * b && b < 10 * a) ? 1 : 0;
        }
    }
}

// ---------------- dest ranks ----------------
__global__ void k_dest(const int* __restrict__ cm, const int* __restrict__ sm,
                       int* __restrict__ meta, int* __restrict__ pdc, int* __restrict__ pds)
{
    int n = blockIdx.x * 256 + threadIdx.x;
    int lane = threadIdx.x & 63;
    unsigned long long below = (1ull << lane) - 1ull;
    int lc = cm[n] & 7, ls = sm[n] & 7;
    int dc = 0, dsv = 0;
    for (int lab = 0; lab < LL; lab++) {
        unsigned long long m = __ballot(lc == lab);
        if (m) {
            int leader = __ffsll((unsigned long long)m) - 1;
            int cntw = __popcll(m);
            int base = 0;
            if (lane == leader) base = atomicAdd(&meta[M_CURC + lab], cntw);
            base = __shfl(base, leader, 64);
            if (lc == lab) dc = base + __popcll(m & below);
        }
        unsigned long long m2 = __ballot(ls == lab);
        if (m2) {
            int leader = __ffsll((unsigned long long)m2) - 1;
            int cntw = __popcll(m2);
            int base = 0;
            if (lane == leader) base = atomicAdd(&meta[M_CURS + lab], cntw);
            base = __shfl(base, leader, 64);
            if (ls == lab) dsv = base + __popcll(m2 & below);
        }
    }
    pdc[n] = dc | (lc << 16);
    pds[n] = dsv | (ls << 16);
}

// ---------------- gather to compacted X + per-label channel sums ----------------
__global__ void k_gather(const float* __restrict__ feat, const int* __restrict__ pd,
                         float* __restrict__ X, float* __restrict__ sums)
{
    __shared__ float sacc[LL][256];
    int t = threadIdx.x;
    int c = blockIdx.y, b = blockIdx.z;
    int n0 = blockIdx.x * 8192;
    for (int r = 0; r < LL; r++) sacc[r][t] = 0.f;
    const float* row = feat + ((size_t)b * CC + c) * NN;
    float* Xrow = X + ((size_t)b * CC + c) * NN;
    for (int it = 0; it < 8; it++) {
        int n = n0 + it * 1024 + t * 4;
        float4 v = *(const float4*)(row + n);
        int4 pp = *(const int4*)(pd + n);
        int d0 = pp.x & 0xFFFF, l0 = pp.x >> 16;
        int d1 = pp.y & 0xFFFF, l1 = pp.y >> 16;
        int d2 = pp.z & 0xFFFF, l2 = pp.z >> 16;
        int d3 = pp.w & 0xFFFF, l3 = pp.w >> 16;
        Xrow[d0] = v.x; sacc[l0][t] += v.x;
        Xrow[d1] = v.y; sacc[l1][t] += v.y;
        Xrow[d2] = v.z; sacc[l2][t] += v.z;
        Xrow[d3] = v.w; sacc[l3][t] += v.w;
    }
    __syncthreads();
    int r = t >> 5, q = t & 31;
    float s = 0.f;
    for (int k = q; k < 256; k += 32) s += sacc[r][k];
    for (int off = 16; off; off >>= 1) s += __shfl_down(s, off, 32);
    if (q == 0) atomicAdd(&sums[((size_t)b * LL + r) * CC + c], s);
}

// ---------------- syrk: Raw[z] += X_tileR * X_tileC^T (lower tile-pairs only) ----------------
__global__ __launch_bounds__(256, 4) void k_syrk(const float* __restrict__ Xc, const float* __restrict__ Xs,
                                                 float* __restrict__ Raw, const int* __restrict__ meta)
{
    int z = blockIdx.z;                 // z = st*16 + b*8 + l
    int l = z & 7, b = (z >> 3) & 1, st = z >> 4;
    if (!meta[M_GUIDE + l]) return;
    int cnt = meta[(st ? M_CNTS : M_CNTC) + l];
    int off = meta[(st ? M_OFFS : M_OFFC) + l];
    int KCH = gridDim.x;
    int clen = (((cnt + KCH - 1) / KCH) + 31) & ~31;
    int p0 = off + blockIdx.x * clen;
    int lend = off + cnt;
    if (p0 >= lend) return;
    int pend = min(p0 + clen, lend);
    int y = blockIdx.y;                 // 0:(0,0) 1:(1,0) 2:(1,1)
    int tR = (y >= 1) ? 128 : 0;
    int tC = (y == 2) ? 128 : 0;

    const float* Xb = (st ? Xs : Xc) + (size_t)b * CC * NN;

    __shared__ float As[32][132];
    __shared__ float Bs[32][132];

    int t = threadIdx.x;
    int ty = t >> 4, tx = t & 15;       // compute: 16x16
    int sr = t & 31, sx = t >> 5;       // staging: row-in-32, px-group

    float acc[8][8];
#pragma unroll
    for (int i = 0; i < 8; i++)
#pragma unroll
        for (int j = 0; j < 8; j++) acc[i][j] = 0.f;

    for (int k0 = p0; k0 < pend; k0 += 32) {
        __syncthreads();
        int p = k0 + sx * 4;
#pragma unroll
        for (int pass = 0; pass < 4; pass++) {
            int row = pass * 32 + sr;
            const float* ap = Xb + (size_t)(tR + row) * NN + p;
            const float* bp = Xb + (size_t)(tC + row) * NN + p;
            float4 av = {0.f, 0.f, 0.f, 0.f}, bv = {0.f, 0.f, 0.f, 0.f};
            if (p + 3 < pend) { av = *(const float4*)ap; bv = *(const float4*)bp; }
            else if (p < pend) {
                int nleft = pend - p;
                for (int j = 0; j < nleft; j++) { ((float*)&av)[j] = ap[j]; ((float*)&bv)[j] = bp[j]; }
            }
            As[sx * 4 + 0][row] = av.x; As[sx * 4 + 1][row] = av.y;
            As[sx * 4 + 2][row] = av.z; As[sx * 4 + 3][row] = av.w;
            Bs[sx * 4 + 0][row] = bv.x; Bs[sx * 4 + 1][row] = bv.y;
            Bs[sx * 4 + 2][row] = bv.z; Bs[sx * 4 + 3][row] = bv.w;
        }
        __syncthreads();
#pragma unroll 4
        for (int kk = 0; kk < 32; kk++) {
            float a[8], bb[8];
#pragma unroll
            for (int i = 0; i < 8; i++) a[i] = As[kk][ty + 16 * i];
#pragma unroll
            for (int j = 0; j < 8; j++) bb[j] = Bs[kk][tx + 16 * j];
#pragma unroll
            for (int i = 0; i < 8; i++)
#pragma unroll
                for (int j = 0; j < 8; j++)
                    acc[i][j] += a[i] * bb[j];
        }
    }

    float* Mb = Raw + (size_t)z * CC * CC;
#pragma unroll
    for (int i = 0; i < 8; i++) {
        int row = tR + ty + 16 * i;
#pragma unroll
        for (int j = 0; j < 8; j++) {
            int col = tC + tx + 16 * j;
            atomicAdd(&Mb[(size_t)row * CC + col], acc[i][j]);
        }
    }
}

// ---------------- finalize: cov = (M2 - a*mu*mu^T)/(a-1), lower triangle only ----------------
__global__ void k_finalize(float* __restrict__ M2c, float* __restrict__ M2s,
                           const float* __restrict__ sums_c, const float* __restrict__ sums_s,
                           const int* __restrict__ meta)
{
    int y = blockIdx.y; int l = y & 7, b = (y >> 3) & 1, st = y >> 4;
    if (!meta[M_GUIDE + l]) return;
    float a = (float)meta[(st ? M_CNTS : M_CNTC) + l];
    float* M = (st ? M2s : M2c) + ((size_t)(b * LL + l)) * CC * CC;
    const float* su = (st ? sums_s : sums_c) + ((size_t)(b * LL + l)) * CC;
    int idx = blockIdx.x * 256 + threadIdx.x;
    int row = idx >> 8, col = idx & 255;
    if (col > row) return;              // only lower triangle is ever consumed
    float mu_r = su[row] / a, mu_c = su[col] / a;
    M[idx] = (M[idx] - a * mu_r * mu_c) / (a - 1.f);
}

// ---------------- blocked Cholesky (panel-in-LDS, one block per matrix) ----------------
__global__ __launch_bounds__(256, 1) void k_chol(float* __restrict__ M2c, float* __restrict__ M2s,
                                                 float* __restrict__ LcT, const int* __restrict__ meta)
{
    int z = blockIdx.x; int l = z & 7, b = (z >> 3) & 1, st = z >> 4;
    if (!meta[M_GUIDE + l]) return;
    float* A = (st ? M2s : M2c) + ((size_t)(b * LL + l)) * CC * CC;
    float* Lt = st ? (float*)0 : (LcT + ((size_t)(b * LL + l)) * CC * CC);
    __shared__ float P[256][67];
    int t = threadIdx.x;
    int tyy = t >> 4, txx = t & 15;

    for (int ps = 0; ps < 4; ps++) {
        int pc = ps * 64, m = 256 - pc;
        // load panel: rows pc..255, cols pc..pc+63
        for (int idx = t; idx < m * 64; idx += 256) {
            int r = idx >> 6, c = idx & 63;
            P[r][c] = A[(size_t)(pc + r) * CC + pc + c];
        }
        __syncthreads();
        // factor 64 columns (right-looking inside panel)
        for (int j = 0; j < 64; j++) {
            float pjj = P[j][j];                 // fully updated; diag kept unsqrt'd
            float inv = 1.0f / sqrtf(fmaxf(pjj, 1e-20f));
            for (int r = j + 1 + t; r < m; r += 256) P[r][j] *= inv;
            __syncthreads();
            for (int r = j + 1 + t; r < m; r += 256) {
                float prj = P[r][j];
                for (int k = j + 1; k < 64; k++)
                    P[r][k] -= prj * P[k][j];
            }
            __syncthreads();
        }
        // write back panel (lower incl diag); diag gets sqrt now
        for (int idx = t; idx < m * 64; idx += 256) {
            int r = idx >> 6, c = idx & 63;
            if (c <= r) {
                float val = P[r][c];
                if (c == r) val = sqrtf(fmaxf(val, 1e-20f));
                A[(size_t)(pc + r) * CC + pc + c] = val;
                if (Lt) Lt[(size_t)(pc + c) * CC + pc + r] = val;
            }
        }
        // trailing update: A[gi][gk] -= P_i * P_k^T for 64-blocks after the panel
        for (int bi = ps + 1; bi < 4; bi++) {
            for (int bk = ps + 1; bk <= bi; bk++) {
                int riB = bi * 64 - pc, rkB = bk * 64 - pc;
                float accT[4][4];
#pragma unroll
                for (int u = 0; u < 4; u++)
#pragma unroll
                    for (int v = 0; v < 4; v++) accT[u][v] = 0.f;
                for (int kx = 0; kx < 64; kx++) {
                    float av[4], bv[4];
#pragma unroll
                    for (int u = 0; u < 4; u++) av[u] = P[riB + tyy * 4 + u][kx];
#pragma unroll
                    for (int v = 0; v < 4; v++) bv[v] = P[rkB + txx * 4 + v][kx];
#pragma unroll
                    for (int u = 0; u < 4; u++)
#pragma unroll
                        for (int v = 0; v < 4; v++) accT[u][v] += av[u] * bv[v];
                }
#pragma unroll
                for (int u = 0; u < 4; u++) {
                    size_t gi = bi * 64 + tyy * 4 + u;
#pragma unroll
                    for (int v = 0; v < 4; v++) {
                        size_t gk = bk * 64 + txx * 4 + v;
                        A[gi * CC + gk] -= accT[u][v];
                    }
                }
            }
        }
        __syncthreads();
    }
}

// ---------------- solve T*Lc = Ls (writes T^T), then v = mu_s - T mu_c ----------------
__global__ __launch_bounds__(256) void k_solve(const float* __restrict__ LcT, const float* __restrict__ M2s,
                                               float* __restrict__ TT, float* __restrict__ vv,
                                               const float* __restrict__ sums_c, const float* __restrict__ sums_s,
                                               const int* __restrict__ meta)
{
    int y = blockIdx.y; int l = y & 7;
    if (!meta[M_GUIDE + l]) return;
    const float* Lc_t = LcT + (size_t)y * CC * CC;
    const float* Ls = M2s + (size_t)y * CC * CC;
    float* Tt = TT + (size_t)y * CC * CC;
    __shared__ float m[32][257];
    __shared__ float lrow[256];
    int t = threadIdx.x;
    int g = t >> 3, tt = t & 7;
    int c = blockIdx.x * 32 + g;
    for (int i = CC - 1; i >= 0; i--) {
        lrow[t] = Lc_t[(size_t)i * CC + t];
        __syncthreads();
        if (c >= i) {
            float s = 0.f;
            for (int k = i + 1 + tt; k <= c; k += 8) s += lrow[k] * m[g][k];
            s += __shfl_down(s, 4, 8);
            s += __shfl_down(s, 2, 8);
            s += __shfl_down(s, 1, 8);
            if (tt == 0) {
                float val = (Ls[(size_t)c * CC + i] - s) / lrow[i];
                m[g][i] = val;
                Tt[(size_t)i * CC + c] = val;
            }
        }
        __syncthreads();
    }
    float aF = (float)meta[M_CNTC + l], bF = (float)meta[M_CNTS + l];
    const float* sc = sums_c + (size_t)y * CC;
    const float* ss = sums_s + (size_t)y * CC;
    float s = 0.f;
    for (int e = tt; e <= c; e += 8) s += m[g][e] * sc[e];
    s += __shfl_down(s, 4, 8);
    s += __shfl_down(s, 2, 8);
    s += __shfl_down(s, 1, 8);
    if (tt == 0) vv[(size_t)y * CC + c] = ss[c] / bF - s / aF;
}

// ---------------- coloring GEMM: O = T*Xc + v ----------------
__global__ __launch_bounds__(256, 4) void k_color(const float* __restrict__ X, const float* __restrict__ TT,
                                                  const float* __restrict__ vv, float* __restrict__ O,
                                                  const int* __restrict__ meta)
{
    int z = blockIdx.z; int b = z >> 3, l = z & 7;
    if (!meta[M_GUIDE + l]) return;
    int cnt = meta[M_CNTC + l], off = meta[M_OFFC + l];
    int lend = off + cnt;
    int p0 = off + blockIdx.x * 128;
    if (p0 >= lend) return;
    int pend = min(p0 + 128, lend);
    int c0 = blockIdx.y * 128;
    int eEnd = c0 + 128;                // T is lower-triangular: e <= c only

    __shared__ float As[32][128];       // T^T rows  [e][c]
    __shared__ float Bs[32][128];       // X rows    [e][p]

    const float* Xb = X + (size_t)b * CC * NN;
    const float* Tb = TT + ((size_t)(b * LL + l)) * CC * CC;
    const float* vb = vv + ((size_t)(b * LL + l)) * CC;
    int t = threadIdx.x;
    int ty = t >> 4, tx = t & 15;
    int w = t >> 6, ln = t & 63;
    int sr = t & 31, sx = t >> 5;
    bool safe = (p0 + 128 <= NN);       // global_load_lds has no per-lane predication

    float acc[8][8];
#pragma unroll
    for (int i = 0; i < 8; i++) {
        float vi = vb[c0 + ty + 16 * i];
#pragma unroll
        for (int j = 0; j < 8; j++) acc[i][j] = vi;
    }

    for (int e0 = 0; e0 < eEnd; e0 += 32) {
        __syncthreads();
        if (safe) {
#pragma unroll
            for (int q = 0; q < 4; q++) {
                int kk = w * 8 + q * 2 + (ln >> 5);
                int cl4 = (ln & 31) * 4;
                gload16(Tb + (size_t)(e0 + kk) * CC + c0 + cl4, &As[w * 8 + q * 2][0]);
                gload16(Xb + (size_t)(e0 + kk) * NN + p0 + cl4, &Bs[w * 8 + q * 2][0]);
            }
        } else {
#pragma unroll
            for (int pass = 0; pass < 4; pass++) {
                int cidx = pass * 32 + sx * 4;
#pragma unroll
                for (int j = 0; j < 4; j++) {
                    As[sr][cidx + j] = Tb[(size_t)(e0 + sr) * CC + c0 + cidx + j];
                    int p = p0 + cidx + j;
                    Bs[sr][cidx + j] = (p < NN) ? Xb[(size_t)(e0 + sr) * NN + p] : 0.f;
                }
            }
        }
        __syncthreads();
#pragma unroll 4
        for (int kk = 0; kk < 32; kk++) {
            float a[8], bb[8];
#pragma unroll
            for (int i = 0; i < 8; i++) a[i] = As[kk][ty + 16 * i];
#pragma unroll
            for (int j = 0; j < 8; j++) bb[j] = Bs[kk][tx + 16 * j];
#pragma unroll
            for (int i = 0; i < 8; i++)
#pragma unroll
                for (int j = 0; j < 8; j++)
                    acc[i][j] += a[i] * bb[j];
        }
    }

    float* Ob = O + (size_t)b * CC * NN;
#pragma unroll
    for (int i = 0; i < 8; i++) {
        int row = c0 + ty + 16 * i;
        float* orow = Ob + (size_t)row * NN;
#pragma unroll
        for (int j = 0; j < 8; j++) {
            int p = p0 + tx + 16 * j;
            if (p < pend) orow[p] = acc[i][j];
        }
    }
}

// ---------------- final scatter ----------------
__global__ void k_scatter(const float* __restrict__ cf, const float* __restrict__ O,
                          const int* __restrict__ pd, float* __restrict__ out,
                          const int* __restrict__ meta)
{
    __shared__ int gd[LL];
    int t = threadIdx.x;
    if (t < LL) gd[t] = meta[M_GUIDE + t];
    __syncthreads();
    int c = blockIdx.y, b = blockIdx.z;
    int n = blockIdx.x * 1024 + t * 4;
    const float* cfr = cf + ((size_t)b * CC + c) * NN;
    const float* Or = O + ((size_t)b * CC + c) * NN;
    float4 v = *(const float4*)(cfr + n);
    int4 pp = *(const int4*)(pd + n);
    float r0 = (gd[pp.x >> 16]) ? Or[pp.x & 0xFFFF] : v.x;
    float r1 = (gd[pp.y >> 16]) ? Or[pp.y & 0xFFFF] : v.y;
    float r2 = (gd[pp.z >> 16]) ? Or[pp.z & 0xFFFF] : v.z;
    float r3 = (gd[pp.w >> 16]) ? Or[pp.w & 0xFFFF] : v.w;
    float4 r = {r0, r1, r2, r3};
    *(float4*)(out + ((size_t)b * CC + c) * NN + n) = r;
}

extern "C" void kernel_launch(void* const* d_in, const int* in_sizes, int n_in,
                              void* d_out, int out_size, void* d_ws, size_t ws_size,
                              hipStream_t stream)
{
    const float* c_feat = (const float*)d_in[0];
    const float* s_feat = (const float*)d_in[1];
    const int* cm = (const int*)d_in[2];
    const int* sm = (const int*)d_in[3];
    float* out = (float*)d_out;

    float* X2 = (float*)d_ws;                              // Xs; later reused as O
    float* M2c = X2 + (size_t)BB * CC * NN;                // B*L*C*C each
    float* M2s = M2c + (size_t)BB * LL * CC * CC;
    float* LcT = M2s + (size_t)BB * LL * CC * CC;
    float* T_T = LcT + (size_t)BB * LL * CC * CC;
    float* sums_c = T_T + (size_t)BB * LL * CC * CC;
    float* sums_s = sums_c + BB * LL * CC;
    float* vv = sums_s + BB * LL * CC;
    int* pdc = (int*)(vv + BB * LL * CC);
    int* pds = pdc + NN;
    int* meta = pds + NN;
    size_t need = (size_t)((char*)(meta + 64) - (char*)d_ws);
    if (ws_size < need) return;

    float* Xc = out;   // d_out doubles as compacted-content scratch until scatter

    hipMemsetAsync(meta, 0, 64 * sizeof(int), stream);
    hipMemsetAsync(sums_c, 0, (size_t)2 * BB * LL * CC * sizeof(float), stream);
    hipMemsetAsync(M2c, 0, (size_t)2 * BB * LL * CC * CC * sizeof(float), stream);
    hipMemsetAsync(T_T, 0, (size_t)BB * LL * CC * CC * sizeof(float), stream);

    k_hist<<<256, 256, 0, stream>>>(cm, sm, meta);
    k_scan<<<1, 64, 0, stream>>>(meta);
    k_dest<<<256, 256, 0, stream>>>(cm, sm, meta, pdc, pds);
    k_gather<<<dim3(8, CC, BB), 256, 0, stream>>>(c_feat, pdc, Xc, sums_c);
    k_gather<<<dim3(8, CC, BB), 256, 0, stream>>>(s_feat, pds, X2, sums_s);
    k_syrk<<<dim3(16, 3, 32), 256, 0, stream>>>(Xc, X2, M2c, meta);
    k_finalize<<<dim3(256, 32), 256, 0, stream>>>(M2c, M2s, sums_c, sums_s, meta);
    k_chol<<<32, 256, 0, stream>>>(M2c, M2s, LcT, meta);
    k_solve<<<dim3(8, 16), 256, 0, stream>>>(LcT, M2s, T_T, vv, sums_c, sums_s, meta);
    k_color<<<dim3(80, 2, 16), 256, 0, stream>>>(Xc, T_T, vv, X2, meta);
    k_scatter<<<dim3(64, CC, BB), 256, 0, stream>>>(c_feat, X2, pdc, out, meta);
}